// Round 10
// baseline (409.058 us; speedup 1.0000x reference)
//
#include <hip/hip_runtime.h>
#include <stdint.h>

// B=128, S=1024, LAST=258, FEAT=255, HIDDEN=1024 — all f32 in/out.
#define NBATCH 128
#define SEQ    1024
#define ROWE   258
#define NPART  8

// ws layout (bytes)
#define WS_KQP   0                       // float kqp[4][128][256]     512 KB
#define WS_PART  524288                  // float part[128][8][260]   1.06 MB

// NOTE (R1): cross-block fusion via __threadfence = L2 wb/inv on gfx950 -> 235 µs attn. Never.
// NOTE (R2/R4): __launch_bounds__(256,W) caps VGPR at ~256/W (W=8->32, W=4->64).
//   Spill signature: small VGPR_Count + WRITE_SIZE >> legit output.
// NOTE (R5-R7): attn rewrites all neutral. R8 3x-attn probe: delta=46.9 us ->
//   attn+gap ~= 23.4 us -> attn IS AT the ~21.5 us streaming floor since R3.
//   The optimization target is the 5-kernel tail + launch gaps, not attn.
// R9: comb+res+h1+h2out fused into ONE per-batch-chain tail_kernel (block owns
//   2 batches; chain is block-local through LDS; no atomics/fences/h1pre).
//   6 kernels -> 3. Weights re-read per block (28 MB/XCD L2 ~= 6.5 us) traded
//   against 3 launches+gaps+intermediate buffers.
// R10: identical resubmit of R9 — R9's bench was an infra failure (container
//   acquisition), the kernel never executed.

static __device__ __forceinline__ float fexp2(float x){ return __builtin_amdgcn_exp2f(x); }

typedef float floatx4 __attribute__((ext_vector_type(4)));
static __device__ __forceinline__ floatx4 load16a8(const float* p) {
    floatx4 r;
    __builtin_memcpy(&r, __builtin_assume_aligned(p, 8), 16);
    return r;
}

// ---------------------------------------------------------------------------
// qk: grid (64 batch-pairs, 4 h-quarters). kqp[hh][b][f] = partial over h-quarter
//     of (qb[h] + sum_j archi[b][j] qW[h][j]) * kW[h][f]. Unscaled; attn sums the
//     4 partials and applies log2(e)/sqrt(258). q.kb dropped (softmax-invariant).
//     (No more h1pre/out zero-init: tail_kernel writes out exactly once.)
__global__ __launch_bounds__(256) void qk_kernel(const float* __restrict__ in,
    const float* __restrict__ kW, const float* __restrict__ qW,
    const float* __restrict__ qb, float* __restrict__ kqp)
{
    __shared__ float qv[2][256];
    const int bb = blockIdx.x;         // 0..63
    const int hh = blockIdx.y;         // 0..3
    const int t  = threadIdx.x;
    const int b0 = bb * 2;
    const int h = hh * 256 + t;
    const float w0 = qW[h * 3 + 0], w1 = qW[h * 3 + 1], w2 = qW[h * 3 + 2], bq = qb[h];
    #pragma unroll
    for (int u = 0; u < 2; u++) {
        const size_t abase = (size_t)(b0 + u) * (SEQ * ROWE) + 255; // input[b,0,255..257]
        qv[u][t] = bq + in[abase] * w0 + in[abase + 1] * w1 + in[abase + 2] * w2;
    }
    __syncthreads();
    const int col = (t < 255) ? t : 254;            // t==255 is a pad slot
    const float* kWp = kW + (size_t)(hh * 256) * 255 + col;
    float acc0 = 0.f, acc1 = 0.f;
    #pragma unroll 16
    for (int i = 0; i < 256; i++) {
        const float kv = kWp[(size_t)i * 255];      // coalesced across t
        acc0 = fmaf(qv[0][i], kv, acc0);            // LDS broadcast reads
        acc1 = fmaf(qv[1][i], kv, acc1);
    }
    kqp[(size_t)((hh << 7) + b0) * 256 + t]       = (t < 255) ? acc0 : 0.f;
    kqp[(size_t)((hh << 7) + b0 + 1) * 256 + t]   = (t < 255) ? acc1 : 0.f;
}

// ---------------------------------------------------------------------------
// attn: unchanged from R7 (probe-verified at streaming floor ~21 us).
// grid (8,128); 64 lanes per row, one dwordx4 per lane per row; 6-step
// butterfly; exp2-domain online softmax; 1-deep row prefetch.
__global__ __launch_bounds__(256, 6) void attn_kernel(const float* __restrict__ in,
                                                      const float* __restrict__ kqp,
                                                      float* __restrict__ part)
{
    __shared__ float sM[4], sL[4], sacc[4][256];
    const int p = blockIdx.x, b = blockIdx.y;
    const int t = threadIdx.x, w = t >> 6, lane = t & 63;

    const float SCALE = (float)(1.4426950408889634 / 16.062378404209142); // log2(e)/sqrt(258)
    float k[4];
    {
        float s0=0.f, s1=0.f, s2=0.f, s3=0.f;
        #pragma unroll
        for (int hh = 0; hh < 4; hh++) {
            const float4 u = *(const float4*)(kqp + (size_t)((hh << 7) + b) * 256 + lane * 4);
            s0 += u.x; s1 += u.y; s2 += u.z; s3 += u.w;
        }
        k[0] = s0 * SCALE; k[1] = s1 * SCALE; k[2] = s2 * SCALE; k[3] = s3 * SCALE;
    }

    const float* rp = in + ((size_t)b * SEQ + p * 128 + w * 32) * ROWE + lane * 4;

    float x[4], xn[4], a[4] = {0.f, 0.f, 0.f, 0.f};
    {
        const floatx4 v = load16a8(rp);
        x[0] = v.x; x[1] = v.y; x[2] = v.z; x[3] = v.w;
    }
    rp += ROWE;
    float m = -INFINITY, l = 0.f;

    #pragma unroll 8
    for (int i = 0; i < 32; i++) {
        if (i < 31) {                      // prefetch next row
            const floatx4 v = load16a8(rp);
            xn[0] = v.x; xn[1] = v.y; xn[2] = v.z; xn[3] = v.w;
            rp += ROWE;
        }
        float d = fmaf(x[0], k[0], fmaf(x[1], k[1], fmaf(x[2], k[2], x[3] * k[3])));
        #pragma unroll
        for (int off = 32; off > 0; off >>= 1) d += __shfl_xor(d, off, 64);
        const float mn = fmaxf(m, d);
        const float cc = fexp2(m - mn);    // first iter: exp2(-inf)=0
        const float wt = fexp2(d - mn);
        l = fmaf(l, cc, wt);
        #pragma unroll
        for (int j = 0; j < 4; j++) a[j] = fmaf(a[j], cc, wt * x[j]);
        m = mn;
        if (i < 31) {
            #pragma unroll
            for (int j = 0; j < 4; j++) x[j] = xn[j];
        }
    }

    #pragma unroll
    for (int j = 0; j < 4; j += 2)
        *(float2*)(&sacc[w][lane * 4 + j]) = make_float2(a[j], a[j+1]);
    if (lane == 0) { sM[w] = m; sL[w] = l; }
    __syncthreads();

    const float M  = fmaxf(fmaxf(sM[0], sM[1]), fmaxf(sM[2], sM[3]));
    const float c0 = fexp2(sM[0] - M), c1 = fexp2(sM[1] - M);
    const float c2 = fexp2(sM[2] - M), c3 = fexp2(sM[3] - M);
    const float acc = c0 * sacc[0][t] + c1 * sacc[1][t] + c2 * sacc[2][t] + c3 * sacc[3][t];
    float* o = part + ((size_t)b * NPART + p) * 260;
    o[t] = acc;
    if (t == 0) {
        o[256] = M;
        o[257] = c0 * sL[0] + c1 * sL[1] + c2 * sL[2] + c3 * sL[3];
    }
}

// ---------------------------------------------------------------------------
// tail: grid (64) x 512 thr. Block g owns batches b0=2g, b0+1. Whole chain
// comb -> res -> h1 -> h2 -> out is block-local through LDS (16 KB):
//   comb: wf[b][f]  = softmax-merge of 8 partials            (t>>8 = batch)
//   res:  resv[b][h]= vb[h] + sum_f wf[b][f]*vW[h][f]        (t owns h=t,t+512)
//   h1:   h1v[b][j] = relu(b1[j] + sum_h resv[b][h]*W1[j][h]) (t owns j=t)
//   h2:   h2v[b][j2]= relu(b2[j2]+ sum_j h1v[b][j]*W2[j2][j]) (t>>8=b, j2=t&255)
//   out:  out[b][o] = b3[o] + sum_j2 h2v[b][j2]*W3[o][j2]     (wave w<4: b=w>>1,o=w&1)
// Weight rows: W1 4KB-aligned, W2 2KB-aligned -> float4; vW rows 1020 B -> scalar.
// Per-thread row streams hit L1 (256 rows x 1 line in flight = 16 KB). Weights
// 3.5 MB/block, 8 blocks/XCD -> ~28 MB/XCD from L2. No atomics, single store.
__global__ __launch_bounds__(512) void tail_kernel(const float* __restrict__ part,
    const float* __restrict__ vW, const float* __restrict__ vb,
    const float* __restrict__ W1, const float* __restrict__ b1,
    const float* __restrict__ W2, const float* __restrict__ b2,
    const float* __restrict__ W3, const float* __restrict__ b3,
    float* __restrict__ out)
{
    __shared__ float wfs[2][256];    // 2 KB
    __shared__ float resv[2][1024];  // 8 KB
    __shared__ float h1v[2][512];    // 4 KB
    __shared__ float h2v[2][256];    // 2 KB
    const int g = blockIdx.x, t = threadIdx.x;
    const int b0 = g * 2;

    // ---- comb ----
    {
        const int bl = t >> 8, f = t & 255;          // bl in {0,1}
        const float* pb = part + (size_t)(b0 + bl) * NPART * 260;
        float M = -INFINITY;
        #pragma unroll
        for (int p = 0; p < NPART; p++) M = fmaxf(M, pb[p * 260 + 256]);
        float L = 0.f, acc = 0.f;
        #pragma unroll
        for (int p = 0; p < NPART; p++) {
            const float cc = fexp2(pb[p * 260 + 256] - M);
            L   = fmaf(cc, pb[p * 260 + 257], L);
            acc = fmaf(cc, pb[p * 260 + f], acc);
        }
        wfs[bl][f] = (f < 255) ? acc / L : 0.f;
    }
    __syncthreads();

    // ---- res ----  (vW rows 255 floats = 1020 B: scalar loads, per-thread row stream)
    #pragma unroll
    for (int r = 0; r < 2; r++) {
        const int h = t + r * 512;
        const float* vr = vW + (size_t)h * 255;
        float a0 = 0.f, a1 = 0.f;
        #pragma unroll 5
        for (int f = 0; f < 255; f++) {
            const float v = vr[f];
            a0 = fmaf(v, wfs[0][f], a0);             // LDS broadcast
            a1 = fmaf(v, wfs[1][f], a1);
        }
        resv[0][h] = a0 + vb[h];
        resv[1][h] = a1 + vb[h];
    }
    __syncthreads();

    // ---- h1 ----  (W1 rows 4 KB-aligned: float4)
    {
        const float* wr = W1 + (size_t)t * 1024;
        float a0 = 0.f, a1 = 0.f;
        #pragma unroll 8
        for (int h = 0; h < 1024; h += 4) {
            const float4 w4 = *(const float4*)(wr + h);
            a0 = fmaf(w4.x, resv[0][h],   fmaf(w4.y, resv[0][h+1],
                 fmaf(w4.z, resv[0][h+2], fmaf(w4.w, resv[0][h+3], a0))));
            a1 = fmaf(w4.x, resv[1][h],   fmaf(w4.y, resv[1][h+1],
                 fmaf(w4.z, resv[1][h+2], fmaf(w4.w, resv[1][h+3], a1))));
        }
        h1v[0][t] = fmaxf(a0 + b1[t], 0.f);
        h1v[1][t] = fmaxf(a1 + b1[t], 0.f);
    }
    __syncthreads();

    // ---- h2 ----  (W2 rows 2 KB-aligned: float4; t>>8 = batch, j2 = t&255)
    {
        const int bl = t >> 8, j2 = t & 255;
        const float* wr = W2 + (size_t)j2 * 512;
        float a = 0.f;
        #pragma unroll 8
        for (int j = 0; j < 512; j += 4) {
            const float4 w4 = *(const float4*)(wr + j);
            a = fmaf(w4.x, h1v[bl][j],   fmaf(w4.y, h1v[bl][j+1],
                fmaf(w4.z, h1v[bl][j+2], fmaf(w4.w, h1v[bl][j+3], a))));
        }
        h2v[bl][j2] = fmaxf(a + b2[j2], 0.f);
    }
    __syncthreads();

    // ---- out ----  (4 dots of 256: wave w<4 handles (b = w>>1, o = w&1))
    {
        const int w = t >> 6, lane = t & 63;
        if (w < 4) {
            const int bl = w >> 1, o = w & 1;
            const float* wr = W3 + o * 256;
            float a = 0.f;
            #pragma unroll
            for (int j = 0; j < 4; j++) {
                const int j2 = lane + j * 64;
                a = fmaf(wr[j2], h2v[bl][j2], a);
            }
            #pragma unroll
            for (int off = 32; off > 0; off >>= 1) a += __shfl_xor(a, off, 64);
            if (lane == 0) out[(b0 + bl) * 2 + o] = a + b3[o];
        }
    }
}

// ---------------------------------------------------------------------------
extern "C" void kernel_launch(void* const* d_in, const int* in_sizes, int n_in,
                              void* d_out, int out_size, void* d_ws, size_t ws_size,
                              hipStream_t stream)
{
    (void)in_sizes; (void)n_in; (void)out_size; (void)ws_size;
    const float* in = (const float*)d_in[0];
    const float* kW = (const float*)d_in[1];
    // d_in[2] = kb: unused — q.kb is a per-batch constant score shift (softmax-invariant)
    const float* vW = (const float*)d_in[3];
    const float* vb = (const float*)d_in[4];
    const float* qW = (const float*)d_in[5];
    const float* qb = (const float*)d_in[6];
    const float* W1 = (const float*)d_in[7];
    const float* b1 = (const float*)d_in[8];
    const float* W2 = (const float*)d_in[9];
    const float* b2 = (const float*)d_in[10];
    const float* W3 = (const float*)d_in[11];
    const float* b3 = (const float*)d_in[12];

    char* ws = (char*)d_ws;
    float* kqp  = (float*)(ws + WS_KQP);
    float* part = (float*)(ws + WS_PART);

    qk_kernel   <<<dim3(64, 4),         256, 0, stream>>>(in, kW, qW, qb, kqp);
    attn_kernel <<<dim3(NPART, NBATCH), 256, 0, stream>>>(in, kqp, part);
    tail_kernel <<<64,                  512, 0, stream>>>(part, vW, vb, W1, b1,
                                                          W2, b2, W3, b3, (float*)d_out);
}

// Round 11
// 328.166 us; speedup vs baseline: 1.2465x; 1.2465x over previous
//
#include <hip/hip_runtime.h>
#include <stdint.h>

// B=128, S=1024, LAST=258, FEAT=255, HIDDEN=1024 — all f32 in/out.
#define NBATCH 128
#define SEQ    1024
#define ROWE   258
#define NPART  8

// ws layout (bytes)
#define WS_KQP   0                       // float kqp[4][128][256]     512 KB
#define WS_PART  524288                  // float part[128][8][260]   1.06 MB

// NOTE (R1): cross-block fusion via __threadfence = L2 wb/inv on gfx950 -> 235 µs attn. Never.
// NOTE (R2/R4): __launch_bounds__(256,W) caps VGPR at ~256/W. Spill signature:
//   small VGPR_Count + WRITE_SIZE >> legit output.
// NOTE (R5-R7): attn rewrites all neutral; R8 3x probe -> attn ~21 us = streaming floor.
// NOTE (R10): fused tail v1 = 180 µs latency crawl: thread-owns-weight-row GEMV
//   -> lane-adjacent threads 4 KB apart -> every wave load = 64 cache lines,
//   uncoalesced, 64 blocks, occupancy 6%. Fusion math verified (absmax 0).
//   Also isolated: old 4-kernel tail ~55 µs incl gaps (the real target).
// R11: tail v2 = wave-per-output-row + butterfly: lanes read 64 consecutive
//   float4 of the weight row (coalesced), input vector hoisted to registers
//   (identical across a wave's rows), rows pipeline. 128 blocks x 1024 thr.

static __device__ __forceinline__ float fexp2(float x){ return __builtin_amdgcn_exp2f(x); }

typedef float floatx4 __attribute__((ext_vector_type(4)));
static __device__ __forceinline__ floatx4 load16a8(const float* p) {
    floatx4 r;
    __builtin_memcpy(&r, __builtin_assume_aligned(p, 8), 16);
    return r;
}
static __device__ __forceinline__ floatx4 load16a4(const float* p) {
    floatx4 r;
    __builtin_memcpy(&r, __builtin_assume_aligned(p, 4), 16);
    return r;
}

// ---------------------------------------------------------------------------
// qk: grid (64 batch-pairs, 4 h-quarters). kqp[hh][b][f] = partial over h-quarter
//     of (qb[h] + sum_j archi[b][j] qW[h][j]) * kW[h][f]. Unscaled; attn sums the
//     4 partials and applies log2(e)/sqrt(258). q.kb dropped (softmax-invariant).
__global__ __launch_bounds__(256) void qk_kernel(const float* __restrict__ in,
    const float* __restrict__ kW, const float* __restrict__ qW,
    const float* __restrict__ qb, float* __restrict__ kqp)
{
    __shared__ float qv[2][256];
    const int bb = blockIdx.x;         // 0..63
    const int hh = blockIdx.y;         // 0..3
    const int t  = threadIdx.x;
    const int b0 = bb * 2;
    const int h = hh * 256 + t;
    const float w0 = qW[h * 3 + 0], w1 = qW[h * 3 + 1], w2 = qW[h * 3 + 2], bq = qb[h];
    #pragma unroll
    for (int u = 0; u < 2; u++) {
        const size_t abase = (size_t)(b0 + u) * (SEQ * ROWE) + 255; // input[b,0,255..257]
        qv[u][t] = bq + in[abase] * w0 + in[abase + 1] * w1 + in[abase + 2] * w2;
    }
    __syncthreads();
    const int col = (t < 255) ? t : 254;            // t==255 is a pad slot
    const float* kWp = kW + (size_t)(hh * 256) * 255 + col;
    float acc0 = 0.f, acc1 = 0.f;
    #pragma unroll 16
    for (int i = 0; i < 256; i++) {
        const float kv = kWp[(size_t)i * 255];      // coalesced across t
        acc0 = fmaf(qv[0][i], kv, acc0);            // LDS broadcast reads
        acc1 = fmaf(qv[1][i], kv, acc1);
    }
    kqp[(size_t)((hh << 7) + b0) * 256 + t]       = (t < 255) ? acc0 : 0.f;
    kqp[(size_t)((hh << 7) + b0 + 1) * 256 + t]   = (t < 255) ? acc1 : 0.f;
}

// ---------------------------------------------------------------------------
// attn: unchanged from R7 (probe-verified at streaming floor ~21 us).
__global__ __launch_bounds__(256, 6) void attn_kernel(const float* __restrict__ in,
                                                      const float* __restrict__ kqp,
                                                      float* __restrict__ part)
{
    __shared__ float sM[4], sL[4], sacc[4][256];
    const int p = blockIdx.x, b = blockIdx.y;
    const int t = threadIdx.x, w = t >> 6, lane = t & 63;

    const float SCALE = (float)(1.4426950408889634 / 16.062378404209142); // log2(e)/sqrt(258)
    float k[4];
    {
        float s0=0.f, s1=0.f, s2=0.f, s3=0.f;
        #pragma unroll
        for (int hh = 0; hh < 4; hh++) {
            const float4 u = *(const float4*)(kqp + (size_t)((hh << 7) + b) * 256 + lane * 4);
            s0 += u.x; s1 += u.y; s2 += u.z; s3 += u.w;
        }
        k[0] = s0 * SCALE; k[1] = s1 * SCALE; k[2] = s2 * SCALE; k[3] = s3 * SCALE;
    }

    const float* rp = in + ((size_t)b * SEQ + p * 128 + w * 32) * ROWE + lane * 4;

    float x[4], xn[4], a[4] = {0.f, 0.f, 0.f, 0.f};
    {
        const floatx4 v = load16a8(rp);
        x[0] = v.x; x[1] = v.y; x[2] = v.z; x[3] = v.w;
    }
    rp += ROWE;
    float m = -INFINITY, l = 0.f;

    #pragma unroll 8
    for (int i = 0; i < 32; i++) {
        if (i < 31) {                      // prefetch next row
            const floatx4 v = load16a8(rp);
            xn[0] = v.x; xn[1] = v.y; xn[2] = v.z; xn[3] = v.w;
            rp += ROWE;
        }
        float d = fmaf(x[0], k[0], fmaf(x[1], k[1], fmaf(x[2], k[2], x[3] * k[3])));
        #pragma unroll
        for (int off = 32; off > 0; off >>= 1) d += __shfl_xor(d, off, 64);
        const float mn = fmaxf(m, d);
        const float cc = fexp2(m - mn);    // first iter: exp2(-inf)=0
        const float wt = fexp2(d - mn);
        l = fmaf(l, cc, wt);
        #pragma unroll
        for (int j = 0; j < 4; j++) a[j] = fmaf(a[j], cc, wt * x[j]);
        m = mn;
        if (i < 31) {
            #pragma unroll
            for (int j = 0; j < 4; j++) x[j] = xn[j];
        }
    }

    #pragma unroll
    for (int j = 0; j < 4; j += 2)
        *(float2*)(&sacc[w][lane * 4 + j]) = make_float2(a[j], a[j+1]);
    if (lane == 0) { sM[w] = m; sL[w] = l; }
    __syncthreads();

    const float M  = fmaxf(fmaxf(sM[0], sM[1]), fmaxf(sM[2], sM[3]));
    const float c0 = fexp2(sM[0] - M), c1 = fexp2(sM[1] - M);
    const float c2 = fexp2(sM[2] - M), c3 = fexp2(sM[3] - M);
    const float acc = c0 * sacc[0][t] + c1 * sacc[1][t] + c2 * sacc[2][t] + c3 * sacc[3][t];
    float* o = part + ((size_t)b * NPART + p) * 260;
    o[t] = acc;
    if (t == 0) {
        o[256] = M;
        o[257] = c0 * sL[0] + c1 * sL[1] + c2 * sL[2] + c3 * sL[3];
    }
}

// ---------------------------------------------------------------------------
// tail v2: grid (128) x 1024 thr (16 waves). Block owns batch b. Chain is
// block-local through LDS. Every GEMV: wave owns an output row; 64 lanes read
// 64 CONSECUTIVE float4 of the weight row (coalesced), the input vector is
// hoisted to registers once per stage (same for all rows a wave does), then a
// 6-step butterfly. Rows independent -> loads pipeline across iterations.
//   res: 1024 rows -> 64/wave.  vW rows 1020 B (4-B aligned): lane 63 clamps
//        base to f=251 and zeroes its first operand (no OOB at h=1023, no
//        double-count of f=251).
//   h1:  512 rows -> 32/wave, 4 passes of 256 floats (W1 rows 4 KB).
//   h2:  256 rows -> 16/wave, 2 passes (W2 rows 2 KB).
//   out: waves 0,1 -> o=0,1.
// Weights 3.5 MB/block < 4 MB L2/XCD -> re-reads are L2 hits.
__global__ __launch_bounds__(1024) void tail_kernel(const float* __restrict__ part,
    const float* __restrict__ vW, const float* __restrict__ vb,
    const float* __restrict__ W1, const float* __restrict__ b1,
    const float* __restrict__ W2, const float* __restrict__ b2,
    const float* __restrict__ W3, const float* __restrict__ b3,
    float* __restrict__ out)
{
    __shared__ float wfs[256];       // 1 KB
    __shared__ float resv[1024];     // 4 KB
    __shared__ float h1v[512];       // 2 KB
    __shared__ float h2v[256];       // 1 KB
    const int b = blockIdx.x, t = threadIdx.x;
    const int w = t >> 6, lane = t & 63;

    // ---- comb (threads 0..255) ----
    if (t < 256) {
        const int f = t;
        const float* pb = part + (size_t)b * NPART * 260;
        float M = -INFINITY;
        #pragma unroll
        for (int p = 0; p < NPART; p++) M = fmaxf(M, pb[p * 260 + 256]);
        float L = 0.f, acc = 0.f;
        #pragma unroll
        for (int p = 0; p < NPART; p++) {
            const float cc = fexp2(pb[p * 260 + 256] - M);
            L   = fmaf(cc, pb[p * 260 + 257], L);
            acc = fmaf(cc, pb[p * 260 + f], acc);
        }
        wfs[f] = (f < 255) ? acc / L : 0.f;
    }
    __syncthreads();

    // ---- res: resv[h] = vb[h] + dot(wf, vW[h][:]) ----
    {
        const int fb = (lane < 63) ? lane * 4 : 251;        // clamp, see header
        float u0 = wfs[fb], u1 = wfs[fb + 1], u2 = wfs[fb + 2], u3 = wfs[fb + 3];
        if (lane == 63) u0 = 0.f;                           // f=251 already covered
        #pragma unroll 4
        for (int i = 0; i < 64; i++) {
            const int h = w * 64 + i;
            const floatx4 v = load16a4(vW + (size_t)h * 255 + fb);
            float d = fmaf(v.x, u0, fmaf(v.y, u1, fmaf(v.z, u2, v.w * u3)));
            #pragma unroll
            for (int off = 32; off > 0; off >>= 1) d += __shfl_xor(d, off, 64);
            if (lane == 0) resv[h] = d + vb[h];
        }
    }
    __syncthreads();

    // ---- h1: h1v[j] = relu(b1[j] + dot(resv, W1[j][:])) ----
    {
        float r[4][4];
        #pragma unroll
        for (int q = 0; q < 4; q++)
            #pragma unroll
            for (int e = 0; e < 4; e++) r[q][e] = resv[q * 256 + lane * 4 + e];
        #pragma unroll 2
        for (int i = 0; i < 32; i++) {
            const int j = w * 32 + i;
            const float* wr = W1 + (size_t)j * 1024 + lane * 4;
            float d = 0.f;
            #pragma unroll
            for (int q = 0; q < 4; q++) {
                const float4 w4 = *(const float4*)(wr + q * 256);
                d = fmaf(w4.x, r[q][0], fmaf(w4.y, r[q][1],
                    fmaf(w4.z, r[q][2], fmaf(w4.w, r[q][3], d))));
            }
            #pragma unroll
            for (int off = 32; off > 0; off >>= 1) d += __shfl_xor(d, off, 64);
            if (lane == 0) h1v[j] = fmaxf(d + b1[j], 0.f);
        }
    }
    __syncthreads();

    // ---- h2: h2v[j2] = relu(b2[j2] + dot(h1v, W2[j2][:])) ----
    {
        float r[2][4];
        #pragma unroll
        for (int q = 0; q < 2; q++)
            #pragma unroll
            for (int e = 0; e < 4; e++) r[q][e] = h1v[q * 256 + lane * 4 + e];
        #pragma unroll 2
        for (int i = 0; i < 16; i++) {
            const int j2 = w * 16 + i;
            const float* wr = W2 + (size_t)j2 * 512 + lane * 4;
            float d = 0.f;
            #pragma unroll
            for (int q = 0; q < 2; q++) {
                const float4 w4 = *(const float4*)(wr + q * 256);
                d = fmaf(w4.x, r[q][0], fmaf(w4.y, r[q][1],
                    fmaf(w4.z, r[q][2], fmaf(w4.w, r[q][3], d))));
            }
            #pragma unroll
            for (int off = 32; off > 0; off >>= 1) d += __shfl_xor(d, off, 64);
            if (lane == 0) h2v[j2] = fmaxf(d + b2[j2], 0.f);
        }
    }
    __syncthreads();

    // ---- out: waves 0,1 -> o = w ----
    if (w < 2) {
        const int o = w;
        const float4 w4 = *(const float4*)(W3 + o * 256 + lane * 4);
        const float h0 = h2v[lane * 4], h1_ = h2v[lane * 4 + 1];
        const float h2_ = h2v[lane * 4 + 2], h3 = h2v[lane * 4 + 3];
        float d = fmaf(w4.x, h0, fmaf(w4.y, h1_, fmaf(w4.z, h2_, w4.w * h3)));
        #pragma unroll
        for (int off = 32; off > 0; off >>= 1) d += __shfl_xor(d, off, 64);
        if (lane == 0) out[b * 2 + o] = d + b3[o];
    }
}

// ---------------------------------------------------------------------------
extern "C" void kernel_launch(void* const* d_in, const int* in_sizes, int n_in,
                              void* d_out, int out_size, void* d_ws, size_t ws_size,
                              hipStream_t stream)
{
    (void)in_sizes; (void)n_in; (void)out_size; (void)ws_size;
    const float* in = (const float*)d_in[0];
    const float* kW = (const float*)d_in[1];
    // d_in[2] = kb: unused — q.kb is a per-batch constant score shift (softmax-invariant)
    const float* vW = (const float*)d_in[3];
    const float* vb = (const float*)d_in[4];
    const float* qW = (const float*)d_in[5];
    const float* qb = (const float*)d_in[6];
    const float* W1 = (const float*)d_in[7];
    const float* b1 = (const float*)d_in[8];
    const float* W2 = (const float*)d_in[9];
    const float* b2 = (const float*)d_in[10];
    const float* W3 = (const float*)d_in[11];
    const float* b3 = (const float*)d_in[12];

    char* ws = (char*)d_ws;
    float* kqp  = (float*)(ws + WS_KQP);
    float* part = (float*)(ws + WS_PART);

    qk_kernel   <<<dim3(64, 4),         256, 0, stream>>>(in, kW, qW, qb, kqp);
    attn_kernel <<<dim3(NPART, NBATCH), 256, 0, stream>>>(in, kqp, part);
    tail_kernel <<<NBATCH,             1024, 0, stream>>>(part, vW, vb, W1, b1,
                                                          W2, b2, W3, b3, (float*)d_out);
}

// Round 12
// 316.820 us; speedup vs baseline: 1.2911x; 1.0358x over previous
//
#include <hip/hip_runtime.h>
#include <stdint.h>

// B=128, S=1024, LAST=258, FEAT=255, HIDDEN=1024 — all f32 in/out.
#define NBATCH 128
#define SEQ    1024
#define ROWE   258
#define NPART  8

// ws layout (bytes)
#define WS_KQP   0                       // float kqp[4][128][256]     512 KB
#define WS_PART  524288                  // float part[128][8][260]   1.06 MB

// NOTE (R1): cross-block fusion via __threadfence = L2 wb/inv on gfx950 -> 235 µs attn. Never.
// NOTE (R2/R4): __launch_bounds__(256,W) caps VGPR at ~256/W. Spill signature:
//   small VGPR_Count + WRITE_SIZE >> legit output.
// NOTE (R5-R8): attn is L3-resident (~8 µs); per-launch gap ~15 µs; fills ~158 µs
//   fixed. Model fits R3/R7/R8/R10/R11. Launch-count is the dominant lever.
// NOTE (R10): tail v1 thread-owns-row: uncoalesced, 180 µs.
// NOTE (R11): tail v2 wave-per-row butterfly: 6-deep ds_bpermute chain per row,
//   672 LDS-pipe ops/wave -> 100 µs latency crawl (VALUBusy 6%).
// R12: tail v3 = 4-lane split-row GEMV: group of 4 lanes owns a row, lane reads
//   consecutive float4s (1 KB/wave-instr over ~16 lines), LDS float4 broadcast
//   operand, 2-step shuffle reduce. Shuffles 672 -> ~30 per wave.

static __device__ __forceinline__ float fexp2(float x){ return __builtin_amdgcn_exp2f(x); }

typedef float floatx4 __attribute__((ext_vector_type(4)));
static __device__ __forceinline__ floatx4 load16a8(const float* p) {
    floatx4 r;
    __builtin_memcpy(&r, __builtin_assume_aligned(p, 8), 16);
    return r;
}
static __device__ __forceinline__ floatx4 load16a4(const float* p) {
    floatx4 r;
    __builtin_memcpy(&r, __builtin_assume_aligned(p, 4), 16);
    return r;
}

// ---------------------------------------------------------------------------
// qk: grid (64 batch-pairs, 4 h-quarters). kqp[hh][b][f] = partial over h-quarter
//     of (qb[h] + sum_j archi[b][j] qW[h][j]) * kW[h][f]. Unscaled; attn sums the
//     4 partials and applies log2(e)/sqrt(258). q.kb dropped (softmax-invariant).
__global__ __launch_bounds__(256) void qk_kernel(const float* __restrict__ in,
    const float* __restrict__ kW, const float* __restrict__ qW,
    const float* __restrict__ qb, float* __restrict__ kqp)
{
    __shared__ float qv[2][256];
    const int bb = blockIdx.x;         // 0..63
    const int hh = blockIdx.y;         // 0..3
    const int t  = threadIdx.x;
    const int b0 = bb * 2;
    const int h = hh * 256 + t;
    const float w0 = qW[h * 3 + 0], w1 = qW[h * 3 + 1], w2 = qW[h * 3 + 2], bq = qb[h];
    #pragma unroll
    for (int u = 0; u < 2; u++) {
        const size_t abase = (size_t)(b0 + u) * (SEQ * ROWE) + 255; // input[b,0,255..257]
        qv[u][t] = bq + in[abase] * w0 + in[abase + 1] * w1 + in[abase + 2] * w2;
    }
    __syncthreads();
    const int col = (t < 255) ? t : 254;            // t==255 is a pad slot
    const float* kWp = kW + (size_t)(hh * 256) * 255 + col;
    float acc0 = 0.f, acc1 = 0.f;
    #pragma unroll 16
    for (int i = 0; i < 256; i++) {
        const float kv = kWp[(size_t)i * 255];      // coalesced across t
        acc0 = fmaf(qv[0][i], kv, acc0);            // LDS broadcast reads
        acc1 = fmaf(qv[1][i], kv, acc1);
    }
    kqp[(size_t)((hh << 7) + b0) * 256 + t]       = (t < 255) ? acc0 : 0.f;
    kqp[(size_t)((hh << 7) + b0 + 1) * 256 + t]   = (t < 255) ? acc1 : 0.f;
}

// ---------------------------------------------------------------------------
// attn: unchanged from R7 (probe-verified ~8 µs, L3-resident input).
__global__ __launch_bounds__(256, 6) void attn_kernel(const float* __restrict__ in,
                                                      const float* __restrict__ kqp,
                                                      float* __restrict__ part)
{
    __shared__ float sM[4], sL[4], sacc[4][256];
    const int p = blockIdx.x, b = blockIdx.y;
    const int t = threadIdx.x, w = t >> 6, lane = t & 63;

    const float SCALE = (float)(1.4426950408889634 / 16.062378404209142); // log2(e)/sqrt(258)
    float k[4];
    {
        float s0=0.f, s1=0.f, s2=0.f, s3=0.f;
        #pragma unroll
        for (int hh = 0; hh < 4; hh++) {
            const float4 u = *(const float4*)(kqp + (size_t)((hh << 7) + b) * 256 + lane * 4);
            s0 += u.x; s1 += u.y; s2 += u.z; s3 += u.w;
        }
        k[0] = s0 * SCALE; k[1] = s1 * SCALE; k[2] = s2 * SCALE; k[3] = s3 * SCALE;
    }

    const float* rp = in + ((size_t)b * SEQ + p * 128 + w * 32) * ROWE + lane * 4;

    float x[4], xn[4], a[4] = {0.f, 0.f, 0.f, 0.f};
    {
        const floatx4 v = load16a8(rp);
        x[0] = v.x; x[1] = v.y; x[2] = v.z; x[3] = v.w;
    }
    rp += ROWE;
    float m = -INFINITY, l = 0.f;

    #pragma unroll 8
    for (int i = 0; i < 32; i++) {
        if (i < 31) {                      // prefetch next row
            const floatx4 v = load16a8(rp);
            xn[0] = v.x; xn[1] = v.y; xn[2] = v.z; xn[3] = v.w;
            rp += ROWE;
        }
        float d = fmaf(x[0], k[0], fmaf(x[1], k[1], fmaf(x[2], k[2], x[3] * k[3])));
        #pragma unroll
        for (int off = 32; off > 0; off >>= 1) d += __shfl_xor(d, off, 64);
        const float mn = fmaxf(m, d);
        const float cc = fexp2(m - mn);    // first iter: exp2(-inf)=0
        const float wt = fexp2(d - mn);
        l = fmaf(l, cc, wt);
        #pragma unroll
        for (int j = 0; j < 4; j++) a[j] = fmaf(a[j], cc, wt * x[j]);
        m = mn;
        if (i < 31) {
            #pragma unroll
            for (int j = 0; j < 4; j++) x[j] = xn[j];
        }
    }

    #pragma unroll
    for (int j = 0; j < 4; j += 2)
        *(float2*)(&sacc[w][lane * 4 + j]) = make_float2(a[j], a[j+1]);
    if (lane == 0) { sM[w] = m; sL[w] = l; }
    __syncthreads();

    const float M  = fmaxf(fmaxf(sM[0], sM[1]), fmaxf(sM[2], sM[3]));
    const float c0 = fexp2(sM[0] - M), c1 = fexp2(sM[1] - M);
    const float c2 = fexp2(sM[2] - M), c3 = fexp2(sM[3] - M);
    const float acc = c0 * sacc[0][t] + c1 * sacc[1][t] + c2 * sacc[2][t] + c3 * sacc[3][t];
    float* o = part + ((size_t)b * NPART + p) * 260;
    o[t] = acc;
    if (t == 0) {
        o[256] = M;
        o[257] = c0 * sL[0] + c1 * sL[1] + c2 * sL[2] + c3 * sL[3];
    }
}

// ---------------------------------------------------------------------------
// tail v3: grid (128) x 1024 thr (16 waves). Block owns batch b; chain
// comb -> res -> h1 -> h2 -> out block-local in 8.5 KB LDS.
// GEMV scheme: wave = 16 groups x 4 lanes (q = lane>>2 row, g = lane&3 chunk).
// Per pass, lane reads ONE float4 of its row at offset p*16+g*4 (lanes of a
// group contiguous 64 B; wave instr = 1 KB over ~16 lines), operand float4
// from LDS (broadcast across groups), 4 FMA. Reduce = 2 shuffles (xor 1,2).
//   res: rows 255 wide -> 15 full passes + clamped tail pass (offset 239+g*4,
//        g==0 zeroes .x to kill the 239 double-count; max idx 254, no OOB).
//   h1:  64 passes (rows 4 KB-aligned). h2: 32 passes.
// Weights 3.5 MB/block, L2-resident per XCD -> ~13-26 µs L2-BW bound.
__global__ __launch_bounds__(1024) void tail_kernel(const float* __restrict__ part,
    const float* __restrict__ vW, const float* __restrict__ vb,
    const float* __restrict__ W1, const float* __restrict__ b1,
    const float* __restrict__ W2, const float* __restrict__ b2,
    const float* __restrict__ W3, const float* __restrict__ b3,
    float* __restrict__ out)
{
    __shared__ float wfs[256];       // 1 KB
    __shared__ float resv[1024];     // 4 KB
    __shared__ float h1v[512];       // 2 KB
    __shared__ float h2v[256];       // 1 KB
    const int b = blockIdx.x, t = threadIdx.x;
    const int w = t >> 6, lane = t & 63;
    const int q = lane >> 2, g = lane & 3;    // row-in-wave, chunk-in-row

    // ---- comb (threads 0..255) ----
    if (t < 256) {
        const int f = t;
        const float* pb = part + (size_t)b * NPART * 260;
        float M = -INFINITY;
        #pragma unroll
        for (int p = 0; p < NPART; p++) M = fmaxf(M, pb[p * 260 + 256]);
        float L = 0.f, acc = 0.f;
        #pragma unroll
        for (int p = 0; p < NPART; p++) {
            const float cc = fexp2(pb[p * 260 + 256] - M);
            L   = fmaf(cc, pb[p * 260 + 257], L);
            acc = fmaf(cc, pb[p * 260 + f], acc);
        }
        wfs[f] = (f < 255) ? acc / L : 0.f;
    }
    __syncthreads();

    // ---- res: resv[h] = vb[h] + dot(wf, vW[h][:255]) ----
    #pragma unroll
    for (int it = 0; it < 4; it++) {
        const int h = it * 256 + w * 16 + q;
        const float* vr = vW + (size_t)h * 255;
        float d = 0.f;
        #pragma unroll
        for (int p = 0; p < 15; p++) {
            const int off = p * 16 + g * 4;
            const floatx4 wv = load16a4(vr + off);
            const float4 u = *(const float4*)(&wfs[off]);   // 16-B aligned, broadcast
            d = fmaf(wv.x, u.x, fmaf(wv.y, u.y, fmaf(wv.z, u.z, fmaf(wv.w, u.w, d))));
        }
        {   // tail pass: offsets 239+g*4 .. +3 (covers 239..254); g==0 zeroes .x
            const int off = 239 + g * 4;
            const floatx4 wv = load16a4(vr + off);
            const float u0 = (g == 0) ? 0.f : wfs[off];
            d = fmaf(wv.x, u0, fmaf(wv.y, wfs[off + 1],
                fmaf(wv.z, wfs[off + 2], fmaf(wv.w, wfs[off + 3], d))));
        }
        d += __shfl_xor(d, 1, 64);
        d += __shfl_xor(d, 2, 64);
        if (g == 0) resv[h] = d + vb[h];
    }
    __syncthreads();

    // ---- h1: h1v[j] = relu(b1[j] + dot(resv, W1[j][:1024])) ----
    #pragma unroll
    for (int it = 0; it < 2; it++) {
        const int j = it * 256 + w * 16 + q;
        const float* wr = W1 + (size_t)j * 1024;
        float d = 0.f;
        #pragma unroll 16
        for (int p = 0; p < 64; p++) {
            const int off = p * 16 + g * 4;
            const float4 wv = *(const float4*)(wr + off);   // rows 4 KB-aligned
            const float4 u = *(const float4*)(&resv[off]);
            d = fmaf(wv.x, u.x, fmaf(wv.y, u.y, fmaf(wv.z, u.z, fmaf(wv.w, u.w, d))));
        }
        d += __shfl_xor(d, 1, 64);
        d += __shfl_xor(d, 2, 64);
        if (g == 0) h1v[j] = fmaxf(d + b1[j], 0.f);
    }
    __syncthreads();

    // ---- h2: h2v[j2] = relu(b2[j2] + dot(h1v, W2[j2][:512])) ----
    {
        const int j2 = w * 16 + q;
        const float* wr = W2 + (size_t)j2 * 512;
        float d = 0.f;
        #pragma unroll 16
        for (int p = 0; p < 32; p++) {
            const int off = p * 16 + g * 4;
            const float4 wv = *(const float4*)(wr + off);   // rows 2 KB-aligned
            const float4 u = *(const float4*)(&h1v[off]);
            d = fmaf(wv.x, u.x, fmaf(wv.y, u.y, fmaf(wv.z, u.z, fmaf(wv.w, u.w, d))));
        }
        d += __shfl_xor(d, 1, 64);
        d += __shfl_xor(d, 2, 64);
        if (g == 0) h2v[j2] = fmaxf(d + b2[j2], 0.f);
    }
    __syncthreads();

    // ---- out: waves 0,1 -> o = w (2 dots of 256, butterfly) ----
    if (w < 2) {
        const int o = w;
        const float4 w4 = *(const float4*)(W3 + o * 256 + lane * 4);
        const float h0 = h2v[lane * 4], h1_ = h2v[lane * 4 + 1];
        const float h2_ = h2v[lane * 4 + 2], h3 = h2v[lane * 4 + 3];
        float d = fmaf(w4.x, h0, fmaf(w4.y, h1_, fmaf(w4.z, h2_, w4.w * h3)));
        #pragma unroll
        for (int off = 32; off > 0; off >>= 1) d += __shfl_xor(d, off, 64);
        if (lane == 0) out[b * 2 + o] = d + b3[o];
    }
}

// ---------------------------------------------------------------------------
extern "C" void kernel_launch(void* const* d_in, const int* in_sizes, int n_in,
                              void* d_out, int out_size, void* d_ws, size_t ws_size,
                              hipStream_t stream)
{
    (void)in_sizes; (void)n_in; (void)out_size; (void)ws_size;
    const float* in = (const float*)d_in[0];
    const float* kW = (const float*)d_in[1];
    // d_in[2] = kb: unused — q.kb is a per-batch constant score shift (softmax-invariant)
    const float* vW = (const float*)d_in[3];
    const float* vb = (const float*)d_in[4];
    const float* qW = (const float*)d_in[5];
    const float* qb = (const float*)d_in[6];
    const float* W1 = (const float*)d_in[7];
    const float* b1 = (const float*)d_in[8];
    const float* W2 = (const float*)d_in[9];
    const float* b2 = (const float*)d_in[10];
    const float* W3 = (const float*)d_in[11];
    const float* b3 = (const float*)d_in[12];

    char* ws = (char*)d_ws;
    float* kqp  = (float*)(ws + WS_KQP);
    float* part = (float*)(ws + WS_PART);

    qk_kernel   <<<dim3(64, 4),         256, 0, stream>>>(in, kW, qW, qb, kqp);
    attn_kernel <<<dim3(NPART, NBATCH), 256, 0, stream>>>(in, kqp, part);
    tail_kernel <<<NBATCH,             1024, 0, stream>>>(part, vW, vb, W1, b1,
                                                          W2, b2, W3, b3, (float*)d_out);
}